// Round 8
// baseline (140.048 us; speedup 1.0000x reference)
//
#include <hip/hip_runtime.h>

// Problem constants
#define BATCH  4
#define SEQL   2048
#define DMODEL 1024
#define NST    16
#define CT     64            // chunk length T
#define NCH    (SEQL / CT)   // 32 chunks

// ws layout (float offsets)
#define WS_P     0           // P[sigma][m]   = (A^(T-1-sigma) B)[m]      : CT*16
#define WS_W     1024        // W[tau][m]     = (B^T A^(tau+1))[m]        : CT*16
#define WS_KV    2048        // kvext[128]: kvext[63+d] = B^T A^d B, 0 for d<0
#define WS_APOW  2176        // Apow[m][k]    = (A^CT)[m][k]              : 256
#define WS_HIN   4096        // hin[b][j][d][m] = s_{j-1}                 : 2M floats

// ---------------------------------------------------------------------------
// Setup: block delta (0..64) computes A^delta in fp64 via binary powering,
// then emits its slice of the tables.
// ---------------------------------------------------------------------------
__global__ __launch_bounds__(256) void setup_tables(const float* __restrict__ A,
                                                    const float* __restrict__ Bv,
                                                    float* __restrict__ ws) {
    __shared__ double buf0[256], buf1[256], buf2[256], buf3[256];
    __shared__ double bd[16], vtmp[16];
    double* S  = buf0;
    double* R  = buf1;
    double* Ta = buf2;
    double* Tb = buf3;
    const int t  = threadIdx.x;
    const int i  = t >> 4;
    const int kk = t & 15;
    const int delta = blockIdx.x;   // 0..64

    S[t] = (double)A[t];
    R[t] = (i == kk) ? 1.0 : 0.0;
    if (t < 16) bd[t] = (double)Bv[t];
    __syncthreads();

    for (int sb = 0; sb < 7; ++sb) {
        if ((delta >> sb) & 1) {
            double acc = 0.0;
            #pragma unroll
            for (int l = 0; l < 16; ++l) acc += R[i * 16 + l] * S[l * 16 + kk];
            Ta[t] = acc;
            __syncthreads();
            double* tmp = R; R = Ta; Ta = tmp;
        }
        if (sb < 6) {
            double acc = 0.0;
            #pragma unroll
            for (int l = 0; l < 16; ++l) acc += S[i * 16 + l] * S[l * 16 + kk];
            Tb[t] = acc;
            __syncthreads();
            double* tmp = S; S = Tb; Tb = tmp;
        }
    }
    // R now holds A^delta (fp64)

    if (delta < CT) {
        if (t < 16) {   // m = t : P[CT-1-delta][m] = (A^delta B)[m]
            double acc = 0.0;
            #pragma unroll
            for (int k = 0; k < 16; ++k) acc += R[t * 16 + k] * bd[k];
            ws[WS_P + (CT - 1 - delta) * 16 + t] = (float)acc;
            vtmp[t] = acc;
        }
        __syncthreads();
        if (t == 0) {   // k_delta = B^T A^delta B
            double kd = 0.0;
            for (int m = 0; m < 16; ++m) kd += bd[m] * vtmp[m];
            ws[WS_KV + 63 + delta] = (float)kd;
        }
    }
    if (delta >= 1 && t < 16) {   // W[delta-1][m] = sum_n B[n] (A^delta)[n][m]
        double acc = 0.0;
        #pragma unroll
        for (int n = 0; n < 16; ++n) acc += bd[n] * R[n * 16 + t];
        ws[WS_W + (delta - 1) * 16 + t] = (float)acc;
    }
    if (delta == CT) ws[WS_APOW + t] = (float)R[t];   // A^CT carry matrix
    if (delta == 0 && t < 63) ws[WS_KV + t] = 0.0f;   // zero-pad negative lags
}

// ---------------------------------------------------------------------------
// K1: chunk state. Block (b, j, quarter-D), 256 threads. x[64][256] staged
// in TWO 32-KB half-stages (second half's loads fly during first half's
// compute). Tables read from global ws (wave-uniform -> scalar cache, NOT
// LDS broadcasts). c_j[m] = sum_sigma P[sigma][m] x[sigma][d].
// ---------------------------------------------------------------------------
__global__ __launch_bounds__(256) void k1_chunkstate(const float* __restrict__ x,
                                                     const float* __restrict__ ws,
                                                     float* __restrict__ cbuf) {
    __shared__ __align__(16) float xs[CT * 256];        // 64 KB
    const int blk = blockIdx.x;           // 512 = ((b*32 + j)*4 + q)
    const int b   = blk >> 7;
    const int j   = (blk >> 2) & 31;
    const int q   = blk & 3;
    const int t   = threadIdx.x;          // 0..255

    const float* __restrict__ xq =
        x + ((size_t)(b * SEQL + j * CT)) * DMODEL + q * 256;   // row stride DMODEL
    const float* __restrict__ P = ws + WS_P;   // uniform -> s_load

    // stage A: sigma rows 0..31 (8 x 1-KB wave runs per wave)
    float4 stA[8];
    #pragma unroll
    for (int k = 0; k < 8; ++k) {
        const int f   = k * 256 + t;      // float4 idx in [0,2048)
        const int row = f >> 6;           // 0..31
        const int c4  = f & 63;
        stA[k] = ((const float4*)(xq + (size_t)row * DMODEL))[c4];
    }
    #pragma unroll
    for (int k = 0; k < 8; ++k) ((float4*)xs)[k * 256 + t] = stA[k];
    __syncthreads();

    // issue stage B loads (rows 32..63) before computing on A
    float4 stB[8];
    #pragma unroll
    for (int k = 0; k < 8; ++k) {
        const int f   = k * 256 + t;
        const int row = 32 + (f >> 6);
        const int c4  = f & 63;
        stB[k] = ((const float4*)(xq + (size_t)row * DMODEL))[c4];
    }

    float c[16];
    #pragma unroll
    for (int m = 0; m < 16; ++m) c[m] = 0.0f;
    #pragma unroll
    for (int s = 0; s < 32; ++s) {        // compute on half A
        const float xv = xs[s * 256 + t];
        #pragma unroll
        for (int m = 0; m < 16; ++m)
            c[m] = fmaf(P[s * 16 + m], xv, c[m]);
    }

    #pragma unroll
    for (int k = 0; k < 8; ++k) ((float4*)xs)[(8 + k) * 256 + t] = stB[k];
    __syncthreads();

    #pragma unroll
    for (int s = 32; s < CT; ++s) {       // compute on half B
        const float xv = xs[s * 256 + t];
        #pragma unroll
        for (int m = 0; m < 16; ++m)
            c[m] = fmaf(P[s * 16 + m], xv, c[m]);
    }

    float4* outp = (float4*)(cbuf + (((size_t)(b * NCH + j) * DMODEL) + q * 256 + t) * 16);
    #pragma unroll
    for (int k = 0; k < 4; ++k)
        outp[k] = make_float4(c[4 * k], c[4 * k + 1], c[4 * k + 2], c[4 * k + 3]);
}

// ---------------------------------------------------------------------------
// K2: carry scan over chunks (unchanged, R3-proven). Thread = (d, m).
// All 32 chunk partials prefetched upfront, then serial shfl chain.
// s_j = Apow*s_{j-1} + c_j ; hin_j = s_{j-1}.
// ---------------------------------------------------------------------------
__global__ __launch_bounds__(256) void k2_carry(const float* __restrict__ cbuf,
                                                float* __restrict__ ws) {
    const int blk = blockIdx.x;           // 256 blocks
    const int b   = blk >> 6;
    const int d0  = (blk & 63) * 16;
    const int t   = threadIdx.x;
    const int m   = t & 15;
    const int ch  = t >> 4;
    const int d   = d0 + ch;
    const int laneBase = t & 48;          // 16-lane group base within wave

    const size_t base0   = (((size_t)(b * NCH) * DMODEL) + d) * 16 + m;
    const size_t jstride = (size_t)DMODEL * 16;

    float cpre[NCH];
    #pragma unroll
    for (int j = 0; j < NCH; ++j)
        cpre[j] = cbuf[base0 + (size_t)j * jstride];

    float Arow[16];
    #pragma unroll
    for (int k = 0; k < 16; ++k) Arow[k] = ws[WS_APOW + m * 16 + k];

    float* hin = ws + WS_HIN;
    float s = 0.0f;
    #pragma unroll
    for (int j = 0; j < NCH; ++j) {
        hin[base0 + (size_t)j * jstride] = s;
        float acc = cpre[j];
        #pragma unroll
        for (int k = 0; k < 16; ++k)
            acc = fmaf(Arow[k], __shfl(s, laneBase + k, 64), acc);
        s = acc;
    }
}

// ---------------------------------------------------------------------------
// K3: outputs. Block (b, j, quarter-D). Two half-stages of x; tau tiles 0,1
// (needing sigma<32) computed on half A while half B loads fly; tiles 2,3
// after. kv/W read from global ws: after full unroll all kv offsets are
// compile-time -> ~79 unique scalars CSE'd into SGPRs (no LDS broadcasts).
// y[tau] = W[tau].h_in + sum_{s<=tau} k[tau-s] x[s]
// ---------------------------------------------------------------------------
__global__ __launch_bounds__(256) void k3_output(const float* __restrict__ x,
                                                 const float* __restrict__ ws,
                                                 float* __restrict__ y) {
    __shared__ __align__(16) float xs[CT * 256];        // 64 KB
    const int blk = blockIdx.x;           // 512 = ((b*32 + j)*4 + q)
    const int b   = blk >> 7;
    const int j   = (blk >> 2) & 31;
    const int q   = blk & 3;
    const int t   = threadIdx.x;          // 0..255
    const int d   = q * 256 + t;

    const float* __restrict__ xq =
        x + ((size_t)(b * SEQL + j * CT)) * DMODEL + q * 256;
    const float* __restrict__ Wt = ws + WS_W;      // uniform -> s_load
    const float* __restrict__ kv = ws + WS_KV + 63;

    // stage A loads (rows 0..31) + h_in loads issued together
    float4 stA[8];
    #pragma unroll
    for (int k = 0; k < 8; ++k) {
        const int f   = k * 256 + t;
        const int row = f >> 6;
        const int c4  = f & 63;
        stA[k] = ((const float4*)(xq + (size_t)row * DMODEL))[c4];
    }
    const float4* hinp = (const float4*)(ws + WS_HIN +
                         (((size_t)(b * NCH + j) * DMODEL) + d) * 16);
    float4 hv[4];
    #pragma unroll
    for (int k = 0; k < 4; ++k) hv[k] = hinp[k];

    #pragma unroll
    for (int k = 0; k < 8; ++k) ((float4*)xs)[k * 256 + t] = stA[k];
    __syncthreads();

    // issue stage B loads (rows 32..63) before computing tiles 0,1
    float4 stB[8];
    #pragma unroll
    for (int k = 0; k < 8; ++k) {
        const int f   = k * 256 + t;
        const int row = 32 + (f >> 6);
        const int c4  = f & 63;
        stB[k] = ((const float4*)(xq + (size_t)row * DMODEL))[c4];
    }

    float h[16];
    #pragma unroll
    for (int k = 0; k < 4; ++k) {
        h[4 * k] = hv[k].x; h[4 * k + 1] = hv[k].y;
        h[4 * k + 2] = hv[k].z; h[4 * k + 3] = hv[k].w;
    }

    float* yp = y + ((size_t)(b * SEQL + j * CT)) * DMODEL + d;

    // tiles 0,1: only need sigma < 32 (half A)
    #pragma unroll
    for (int tt = 0; tt < 2; ++tt) {
        float yv[16];
        #pragma unroll
        for (int i = 0; i < 16; ++i) {
            float acc = 0.0f;
            #pragma unroll
            for (int m = 0; m < 16; ++m)
                acc = fmaf(Wt[(tt * 16 + i) * 16 + m], h[m], acc);
            yv[i] = acc;
        }
        #pragma unroll
        for (int s = 0; s < tt * 16 + 16; ++s) {
            const float xv = xs[s * 256 + t];
            #pragma unroll
            for (int i = 0; i < 16; ++i)       // tau<s hits kv zero-pad
                yv[i] = fmaf(kv[tt * 16 + i - s], xv, yv[i]);
        }
        #pragma unroll
        for (int i = 0; i < 16; ++i)
            yp[(size_t)(tt * 16 + i) * DMODEL] = yv[i];
    }

    #pragma unroll
    for (int k = 0; k < 8; ++k) ((float4*)xs)[(8 + k) * 256 + t] = stB[k];
    __syncthreads();

    // tiles 2,3: need full sigma range
    #pragma unroll
    for (int tt = 2; tt < 4; ++tt) {
        float yv[16];
        #pragma unroll
        for (int i = 0; i < 16; ++i) {
            float acc = 0.0f;
            #pragma unroll
            for (int m = 0; m < 16; ++m)
                acc = fmaf(Wt[(tt * 16 + i) * 16 + m], h[m], acc);
            yv[i] = acc;
        }
        #pragma unroll
        for (int s = 0; s < tt * 16 + 16; ++s) {
            const float xv = xs[s * 256 + t];
            #pragma unroll
            for (int i = 0; i < 16; ++i)
                yv[i] = fmaf(kv[tt * 16 + i - s], xv, yv[i]);
        }
        #pragma unroll
        for (int i = 0; i < 16; ++i)
            yp[(size_t)(tt * 16 + i) * DMODEL] = yv[i];
    }
}

// ---------------------------------------------------------------------------
extern "C" void kernel_launch(void* const* d_in, const int* in_sizes, int n_in,
                              void* d_out, int out_size, void* d_ws, size_t ws_size,
                              hipStream_t stream) {
    (void)in_sizes; (void)n_in; (void)out_size; (void)ws_size;
    const float* x  = (const float*)d_in[0];
    const float* A  = (const float*)d_in[1];
    const float* Bv = (const float*)d_in[2];
    float* out = (float*)d_out;
    float* ws  = (float*)d_ws;

    // c scratch lives in d_out (dead before K3 overwrites it with y);
    // h_in + tables in ws.
    setup_tables<<<65, 256, 0, stream>>>(A, Bv, ws);
    k1_chunkstate<<<512, 256, 0, stream>>>(x, ws, out);
    k2_carry<<<256, 256, 0, stream>>>(out, ws);
    k3_output<<<512, 256, 0, stream>>>(x, ws, out);
}